// Round 11
// baseline (321.050 us; speedup 1.0000x reference)
//
#include <hip/hip_runtime.h>

#define BATCH 16
#define CH    256
#define NPT   2048
#define DQK   32
#define OTOT  320   // 32 q + 32 k + 256 v
#define EPSB  1e-5f
#define SLOPE 0.2f

typedef __attribute__((ext_vector_type(8))) short bf16x8;
typedef __attribute__((ext_vector_type(4))) float f32x4;

__device__ __forceinline__ unsigned short f2bf(float f) {
    unsigned u = __float_as_uint(f);
    u = (u + 0x7FFFu + ((u >> 16) & 1u)) >> 16;
    return (unsigned short)u;
}
__device__ __forceinline__ float bf2f(unsigned short h) {
    return __uint_as_float(((unsigned)h) << 16);
}
// pack two f32 -> dword of 2 bf16 (lo = a, hi = b), RNE in HW
__device__ __forceinline__ unsigned cvt_pk_bf16(float a, float b) {
    unsigned r;
    asm("v_cvt_pk_bf16_f32 %0, %1, %2" : "=v"(r) : "v"(a), "v"(b));
    return r;
}

// ---------------------------------------------------------------------------
// Kernel 0: split weights to Whi/Wlo bf16 [o][c] (A-frag layout) + bias Bv[o].
// grid 320 x 256.
__global__ __launch_bounds__(256) void prep_kernel(
    const float* __restrict__ qw, const float* __restrict__ qb,
    const float* __restrict__ kw, const float* __restrict__ kb,
    const float* __restrict__ vw, const float* __restrict__ vb,
    unsigned short* __restrict__ Whi, unsigned short* __restrict__ Wlo,
    float* __restrict__ Bv)
{
    int idx = blockIdx.x * 256 + threadIdx.x;   // < 81920
    int o = idx >> 8, c = idx & 255;
    float w;
    if (o < 32)      w = qw[(size_t)o * CH + c];
    else if (o < 64) w = kw[(size_t)(o - 32) * CH + c];
    else             w = vw[(size_t)(o - 64) * CH + c];
    unsigned short wh = f2bf(w);
    float rem = w - bf2f(wh);
    Whi[idx] = wh;
    Wlo[idx] = f2bf(rem);
    if (idx < OTOT) {
        int oo = idx;
        float bb;
        if (oo < 32)      bb = qb[oo];
        else if (oo < 64) bb = kb[oo - 32];
        else              bb = vb[oo - 64];
        Bv[oo] = bb;
    }
}

// ---------------------------------------------------------------------------
// Kernel 1: conv1x1 as bf16x3 MFMA GEMM (fp32-grade precision).
// Block: 64o x 128n for one b. grid 1280 linear, block 256 (waves 2o x 2n).
// XCD-chunked swizzle (1280 = 8*160) so the 5 o-blocks sharing one 128KB
// x-tile land on the SAME XCD -> x L2-resident.
// Fused: bias, bf16 store, per-channel sum/sumsq atomics.
__global__ __launch_bounds__(256) void conv_kernel(
    const float* __restrict__ x,
    const unsigned short* __restrict__ Whi, const unsigned short* __restrict__ Wlo,
    const float* __restrict__ Bv,
    unsigned short* __restrict__ Ybf,
    float* __restrict__ Sum, float* __restrict__ Sq)
{
    int lin = blockIdx.x;
    int vid = (lin & 7) * 160 + (lin >> 3);
    int o5  = vid % 5;
    int rem = vid / 5;            // 0..255
    int ob = o5 * 64;
    int n0 = (rem & 15) * 128;
    int b  = rem >> 4;

    int tid = threadIdx.x;
    int w = tid >> 6, lane = tid & 63;
    int quad = lane >> 4, l16 = lane & 15;
    int wo = w >> 1, wn = w & 1;

    __shared__ unsigned short Xh[128][40];   // [n_local][c_local], stride 80B
    __shared__ unsigned short Xl[128][40];

    int nl = tid & 127;       // n_local 0..127
    int ch = tid >> 7;        // c half
    const float* xb = x + (size_t)b * CH * NPT + n0 + nl;

    f32x4 acc[2][4];
#pragma unroll
    for (int ot = 0; ot < 2; ++ot)
#pragma unroll
        for (int nt = 0; nt < 4; ++nt)
            acc[ot][nt] = (f32x4){0.f, 0.f, 0.f, 0.f};

    float xv[16];
#pragma unroll
    for (int i = 0; i < 16; ++i)
        xv[i] = xb[(size_t)(ch * 16 + i) * NPT];

    for (int ks = 0; ks < 8; ++ks) {
        __syncthreads();
#pragma unroll
        for (int g = 0; g < 4; ++g) {
            ushort4 h4, l4;
            unsigned short* ph = (unsigned short*)&h4;
            unsigned short* pl = (unsigned short*)&l4;
#pragma unroll
            for (int j = 0; j < 4; ++j) {
                float f = xv[g * 4 + j];
                unsigned short h = f2bf(f);
                ph[j] = h;
                pl[j] = f2bf(f - bf2f(h));
            }
            *(ushort4*)&Xh[nl][ch * 16 + g * 4] = h4;
            *(ushort4*)&Xl[nl][ch * 16 + g * 4] = l4;
        }
        __syncthreads();

        if (ks < 7) {
#pragma unroll
            for (int i = 0; i < 16; ++i)
                xv[i] = xb[(size_t)((ks + 1) * 32 + ch * 16 + i) * NPT];
        }

        bf16x8 ah[2], al[2];
#pragma unroll
        for (int ot = 0; ot < 2; ++ot) {
            size_t orow = (size_t)(ob + wo * 32 + ot * 16 + l16) * 256 + ks * 32 + quad * 8;
            ah[ot] = *(const bf16x8*)(Whi + orow);
            al[ot] = *(const bf16x8*)(Wlo + orow);
        }
#pragma unroll
        for (int nt = 0; nt < 4; ++nt) {
            int nr = wn * 64 + nt * 16 + l16;
            bf16x8 bh = *(const bf16x8*)&Xh[nr][quad * 8];
            bf16x8 bl = *(const bf16x8*)&Xl[nr][quad * 8];
#pragma unroll
            for (int ot = 0; ot < 2; ++ot) {
                acc[ot][nt] = __builtin_amdgcn_mfma_f32_16x16x32_bf16(ah[ot], bh, acc[ot][nt], 0, 0, 0);
                acc[ot][nt] = __builtin_amdgcn_mfma_f32_16x16x32_bf16(ah[ot], bl, acc[ot][nt], 0, 0, 0);
                acc[ot][nt] = __builtin_amdgcn_mfma_f32_16x16x32_bf16(al[ot], bh, acc[ot][nt], 0, 0, 0);
            }
        }
    }

#pragma unroll
    for (int ot = 0; ot < 2; ++ot) {
        int obase = ob + wo * 32 + ot * 16 + quad * 4;
        float bias[4], sv[4], sq[4];
#pragma unroll
        for (int r = 0; r < 4; ++r) {
            bias[r] = Bv[obase + r];
            sv[r] = 0.f; sq[r] = 0.f;
        }
#pragma unroll
        for (int nt = 0; nt < 4; ++nt) {
            int n = n0 + wn * 64 + nt * 16 + l16;
#pragma unroll
            for (int r = 0; r < 4; ++r) {
                float v = acc[ot][nt][r] + bias[r];
                Ybf[((size_t)b * OTOT + obase + r) * NPT + n] = f2bf(v);
                sv[r] += v; sq[r] += v * v;
            }
        }
#pragma unroll
        for (int r = 0; r < 4; ++r) {
            float a = sv[r], q = sq[r];
            a += __shfl_xor(a, 1); q += __shfl_xor(q, 1);
            a += __shfl_xor(a, 2); q += __shfl_xor(q, 2);
            a += __shfl_xor(a, 4); q += __shfl_xor(q, 4);
            a += __shfl_xor(a, 8); q += __shfl_xor(q, 8);
            if (l16 == 0) {
                atomicAdd(&Sum[obase + r], a);
                atomicAdd(&Sq[obase + r], q);
            }
        }
    }
}

// ---------------------------------------------------------------------------
// Kernel 3: pack pass — v: affine+LeakyReLU -> Vbf [b][c][n];
//                       q/k: affine + transpose -> QKt [b][n][64].
// BN-finalize inlined per block (finalize_kernel removed). grid (32,16).
__global__ __launch_bounds__(256) void pack_kernel(
    const unsigned short* __restrict__ Ybf,
    const float* __restrict__ Sum, const float* __restrict__ Sq,
    const float* __restrict__ qg, const float* __restrict__ qbe,
    const float* __restrict__ kg, const float* __restrict__ kbe,
    const float* __restrict__ vg, const float* __restrict__ vbe,
    unsigned short* __restrict__ QKt, unsigned short* __restrict__ Vbf)
{
    int b = blockIdx.y, n0 = blockIdx.x * 64;
    int tid = threadIdx.x;

    __shared__ float sA[OTOT], sC[OTOT];
    for (int o = tid; o < OTOT; o += 256) {
        const float inv = 1.0f / (BATCH * NPT);
        float mean = Sum[o] * inv;
        float var  = Sq[o] * inv - mean * mean;
        float g, be;
        if (o < 32)      { g = qg[o];      be = qbe[o];      }
        else if (o < 64) { g = kg[o - 32]; be = kbe[o - 32]; }
        else             { g = vg[o - 64]; be = vbe[o - 64]; }
        float a = g * rsqrtf(var + EPSB);
        sA[o] = a;
        sC[o] = be - mean * a;
    }
    __syncthreads();

    for (int e = tid; e < 4096; e += 256) {
        int c = e >> 4, n4 = (e & 15) * 4;
        ushort4 v4 = *(const ushort4*)(Ybf + ((size_t)b * OTOT + 64 + c) * NPT + n0 + n4);
        float a = sA[64 + c], cc = sC[64 + c];
        ushort4 w4;
        unsigned short* pi = (unsigned short*)&v4;
        unsigned short* po = (unsigned short*)&w4;
#pragma unroll
        for (int i = 0; i < 4; ++i) {
            float y = bf2f(pi[i]) * a + cc;
            y = (y > 0.f) ? y : SLOPE * y;
            po[i] = f2bf(y);
        }
        *(ushort4*)(Vbf + ((size_t)b * CH + c) * NPT + n0 + n4) = w4;
    }

    __shared__ unsigned short T[64][72];
    for (int e = tid; e < 1024; e += 256) {
        int o = e >> 4, n4 = (e & 15) * 4;
        ushort4 v4 = *(const ushort4*)(Ybf + ((size_t)b * OTOT + o) * NPT + n0 + n4);
        float a = sA[o], cc = sC[o];
        unsigned short* pi = (unsigned short*)&v4;
#pragma unroll
        for (int i = 0; i < 4; ++i)
            T[n4 + i][o] = f2bf(bf2f(pi[i]) * a + cc);
    }
    __syncthreads();
    for (int e = tid; e < 1024; e += 256) {
        int nn = e >> 4, o4 = (e & 15) * 4;
        ushort4 v4 = *(const ushort4*)&T[nn][o4];
        *(ushort4*)(QKt + ((size_t)b * NPT + n0 + nn) * 64 + o4) = v4;
    }
}

// ---------------------------------------------------------------------------
// Kernel 4: MFMA flash attention, max-free softmax, + residual.
// v10: n0-SPLIT for TLP without duplication. v9 (z-merged) fell to 2
//     blocks/CU (occupancy 20%) and the serial chain had nothing to overlap
//     with. Splitting the q-row range 64->32 per block (nt 4->2, Pbf 32 rows,
//     acc[2][4]) doubles the grid to 1024 = 4 blocks/CU while keeping TOTAL
//     QK/exp/P-LDS/PV work exactly constant (unlike v5's c-split, which
//     duplicated QK+exp and regressed 2x). Only K/V register re-reads
//     duplicate (~4us of L2 BW, absorbed). Loop body otherwise identical to
//     v9. Per-output accumulation order unchanged -> absmax 0.109375.
// grid 1024 (XCD decode: 2 b per XCD), block 256 (4 waves), 4 blocks/CU.
__global__ __launch_bounds__(256, 4) void attn_kernel(
    const unsigned short* __restrict__ QKt,
    const unsigned short* __restrict__ Vbf,
    const float* __restrict__ x,
    float* __restrict__ out)
{
    int L = blockIdx.x;
    int xcd = L & 7, k = L >> 3;      // k in [0,128)
    int gi = k >> 6, n0i = k & 63;    // gi in [0,2), n0i in [0,64)
    int b = xcd * 2 + gi;             // [0,16)
    int n0 = n0i * 32;

    int tid = threadIdx.x;
    int w = tid >> 6, lane = tid & 63;
    int quad = lane >> 4, l16 = lane & 15;

    const unsigned short* QK = QKt + (size_t)b * NPT * 64;
    const unsigned short* V  = Vbf + (size_t)b * CH * NPT;

    __shared__ unsigned short Pbf[2][32][72];   // [buf][n][m], stride 144B
    __shared__ float rsw[4][32];
    __shared__ float rtot[32];

    // Q fragments: rows n = n0+nt*16+l16, k-slice quad*8
    bf16x8 qa[2];
#pragma unroll
    for (int nt = 0; nt < 2; ++nt)
        qa[nt] = *(const bf16x8*)(QK + ((size_t)(n0 + nt * 16 + l16)) * 64 + quad * 8);

    f32x4 acc[2][4];   // [nt][ct]: n = n0+nt*16+quad*4.., c = w*64+ct*16+l16
#pragma unroll
    for (int nt = 0; nt < 2; ++nt)
#pragma unroll
        for (int ct = 0; ct < 4; ++ct)
            acc[nt][ct] = (f32x4){0.f, 0.f, 0.f, 0.f};

    // per-lane softmax partials: n = nt*16+l16, m in {w*16+quad*4 ..+3} per tile
    float rsum[2];
#pragma unroll
    for (int nt = 0; nt < 2; ++nt) rsum[nt] = 0.f;

    const f32x4 zero4 = (f32x4){0.f, 0.f, 0.f, 0.f};

    // K fragment for m-tile 0: rows m = w*16+l16, k-slice quad*8 (K half: +32)
    bf16x8 kb = *(const bf16x8*)(QK + ((size_t)(w * 16 + l16)) * 64 + 32 + quad * 8);

    for (int mt = 0; mt < NPT / 64; ++mt) {
        unsigned short (*Pb)[72] = Pbf[mt & 1];

        // QK^T swapped: S[m = w*16+quad*4+r][n = nt*16+l16]
        f32x4 s[2];
#pragma unroll
        for (int nt = 0; nt < 2; ++nt)
            s[nt] = __builtin_amdgcn_mfma_f32_16x16x32_bf16(kb, qa[nt], zero4, 0, 0, 0);

        // prefetch next K tile; completes under exp/pack + barrier drain
        if (mt < NPT / 64 - 1)
            kb = *(const bf16x8*)(QK + ((size_t)((mt + 1) * 64 + w * 16 + l16)) * 64 + 32 + quad * 8);

        // V fragments for THIS tile (8 = ks2 x ct4), issued before exp/pack so
        // L2 latency hides under exp + barrier arrival (barrier drains vmcnt).
        bf16x8 vb[8];
#pragma unroll
        for (int u = 0; u < 8; ++u)
            vb[u] = *(const bf16x8*)(V + ((size_t)(w * 64 + (u & 3) * 16 + l16)) * NPT
                                     + mt * 64 + (u >> 2) * 32 + quad * 8);

#pragma unroll
        for (int nt = 0; nt < 2; ++nt) {
            float p0 = __expf(s[nt][0]);        // max-free: |s| << 88
            float p1 = __expf(s[nt][1]);
            float p2 = __expf(s[nt][2]);
            float p3 = __expf(s[nt][3]);
            rsum[nt] += (p0 + p1) + (p2 + p3);
            uint2 dd;
            dd.x = cvt_pk_bf16(p0, p1);
            dd.y = cvt_pk_bf16(p2, p3);
            // 4 m-consecutive bf16 at P[n][w*16+quad*4]; bank-floor pattern
            *(uint2*)&Pb[nt * 16 + l16][w * 16 + quad * 4] = dd;
        }

        __syncthreads();   // P[buf] visible; buffer alternation covers WAR

#pragma unroll
        for (int ks = 0; ks < 2; ++ks) {
            bf16x8 pa[2];
#pragma unroll
            for (int nt = 0; nt < 2; ++nt)
                pa[nt] = *(const bf16x8*)&Pb[nt * 16 + l16][ks * 32 + quad * 8];
#pragma unroll
            for (int ct = 0; ct < 4; ++ct) {
                bf16x8 vv = vb[ks * 4 + ct];
#pragma unroll
                for (int nt = 0; nt < 2; ++nt)
                    acc[nt][ct] = __builtin_amdgcn_mfma_f32_16x16x32_bf16(pa[nt], vv, acc[nt][ct], 0, 0, 0);
            }
        }
    }

    // reduce rsum over quads (m-subchunks), then over waves via LDS
#pragma unroll
    for (int nt = 0; nt < 2; ++nt) {
        float v = rsum[nt];
        v += __shfl_xor(v, 16);
        v += __shfl_xor(v, 32);
        if (lane < 16) rsw[w][nt * 16 + lane] = v;
    }
    __syncthreads();
    if (tid < 32)
        rtot[tid] = 1.0f / (rsw[0][tid] + rsw[1][tid] + rsw[2][tid] + rsw[3][tid]);
    __syncthreads();

    float rin[2][4];
#pragma unroll
    for (int nt = 0; nt < 2; ++nt)
#pragma unroll
        for (int r = 0; r < 4; ++r) rin[nt][r] = rtot[nt * 16 + quad * 4 + r];

#pragma unroll
    for (int nt = 0; nt < 2; ++nt)
#pragma unroll
        for (int ct = 0; ct < 4; ++ct) {
            int c = w * 64 + ct * 16 + l16;
            int n = n0 + nt * 16 + quad * 4;
            size_t gi4 = ((size_t)b * CH + c) * NPT + n;
            float4 xv = *(const float4*)(x + gi4);
            float4 o;
            o.x = acc[nt][ct][0] * rin[nt][0] + xv.x;
            o.y = acc[nt][ct][1] * rin[nt][1] + xv.y;
            o.z = acc[nt][ct][2] * rin[nt][2] + xv.z;
            o.w = acc[nt][ct][3] * rin[nt][3] + xv.w;
            *(float4*)(out + gi4) = o;
        }
}

// ---------------------------------------------------------------------------
extern "C" void kernel_launch(void* const* d_in, const int* in_sizes, int n_in,
                              void* d_out, int out_size, void* d_ws, size_t ws_size,
                              hipStream_t stream)
{
    const float* x   = (const float*)d_in[0];
    const float* qw  = (const float*)d_in[1];
    const float* qb  = (const float*)d_in[2];
    const float* qg  = (const float*)d_in[3];
    const float* qbe = (const float*)d_in[4];
    const float* kw  = (const float*)d_in[5];
    const float* kb  = (const float*)d_in[6];
    const float* kg  = (const float*)d_in[7];
    const float* kbe = (const float*)d_in[8];
    const float* vw  = (const float*)d_in[9];
    const float* vb  = (const float*)d_in[10];
    const float* vg  = (const float*)d_in[11];
    const float* vbe = (const float*)d_in[12];
    float* out = (float*)d_out;

    // ws: Ybf (21MB) | QKt (4.2MB; head reused as Whi/Wlo/Bv before pack) | Vbf (16.8MB)
    //     | Sum,Sq (2.5KB)
    unsigned short* Ybf = (unsigned short*)d_ws;
    unsigned short* QKt = Ybf + (size_t)BATCH * OTOT * NPT;          // 10,485,760 elems
    unsigned short* Vbf = QKt + (size_t)BATCH * NPT * 64;            // +2,097,152
    float* tail = (float*)(Vbf + (size_t)BATCH * CH * NPT);          // +8,388,608
    float* Sum = tail;
    float* Sq  = tail + OTOT;
    // overlay: Whi/Wlo/Bv live in QKt region, consumed (conv) before pack writes QKt
    unsigned short* Whi = QKt;                         // 81,920 ushorts
    unsigned short* Wlo = Whi + (size_t)CH * OTOT;     // 81,920 ushorts
    float* Bv = (float*)(Wlo + (size_t)CH * OTOT);     // 320 floats

    hipMemsetAsync(Sum, 0, 2 * OTOT * sizeof(float), stream);
    prep_kernel <<<320, 256, 0, stream>>>(qw, qb, kw, kb, vw, vb, Whi, Wlo, Bv);
    conv_kernel <<<1280, 256, 0, stream>>>(x, Whi, Wlo, Bv, Ybf, Sum, Sq);
    pack_kernel <<<dim3(NPT / 64, BATCH), 256, 0, stream>>>(
        Ybf, Sum, Sq, qg, qbe, kg, kbe, vg, vbe, QKt, Vbf);
    attn_kernel <<<1024, 256, 0, stream>>>(QKt, Vbf, x, out);
}

// Round 13
// 260.151 us; speedup vs baseline: 1.2341x; 1.2341x over previous
//
#include <hip/hip_runtime.h>

#define BATCH 16
#define CH    256
#define NPT   2048
#define DQK   32
#define OTOT  320   // 32 q + 32 k + 256 v
#define EPSB  1e-5f
#define SLOPE 0.2f

typedef __attribute__((ext_vector_type(8))) short bf16x8;
typedef __attribute__((ext_vector_type(4))) float f32x4;

__device__ __forceinline__ unsigned short f2bf(float f) {
    unsigned u = __float_as_uint(f);
    u = (u + 0x7FFFu + ((u >> 16) & 1u)) >> 16;
    return (unsigned short)u;
}
__device__ __forceinline__ float bf2f(unsigned short h) {
    return __uint_as_float(((unsigned)h) << 16);
}
// pack two f32 -> dword of 2 bf16 (lo = a, hi = b), RNE in HW
__device__ __forceinline__ unsigned cvt_pk_bf16(float a, float b) {
    unsigned r;
    asm("v_cvt_pk_bf16_f32 %0, %1, %2" : "=v"(r) : "v"(a), "v"(b));
    return r;
}

// ---------------------------------------------------------------------------
// Kernel 0: split weights to Whi/Wlo bf16 [o][c] (A-frag layout) + bias Bv[o].
// grid 320 x 256.
__global__ __launch_bounds__(256) void prep_kernel(
    const float* __restrict__ qw, const float* __restrict__ qb,
    const float* __restrict__ kw, const float* __restrict__ kb,
    const float* __restrict__ vw, const float* __restrict__ vb,
    unsigned short* __restrict__ Whi, unsigned short* __restrict__ Wlo,
    float* __restrict__ Bv)
{
    int idx = blockIdx.x * 256 + threadIdx.x;   // < 81920
    int o = idx >> 8, c = idx & 255;
    float w;
    if (o < 32)      w = qw[(size_t)o * CH + c];
    else if (o < 64) w = kw[(size_t)(o - 32) * CH + c];
    else             w = vw[(size_t)(o - 64) * CH + c];
    unsigned short wh = f2bf(w);
    float rem = w - bf2f(wh);
    Whi[idx] = wh;
    Wlo[idx] = f2bf(rem);
    if (idx < OTOT) {
        int oo = idx;
        float bb;
        if (oo < 32)      bb = qb[oo];
        else if (oo < 64) bb = kb[oo - 32];
        else              bb = vb[oo - 64];
        Bv[oo] = bb;
    }
}

// ---------------------------------------------------------------------------
// Kernel 1: conv1x1 as bf16x3 MFMA GEMM (fp32-grade precision).
// Block: 64o x 128n for one b. grid 1280 linear, block 256 (waves 2o x 2n).
// XCD-chunked swizzle (1280 = 8*160) so the 5 o-blocks sharing one 128KB
// x-tile land on the SAME XCD -> x L2-resident.
// Fused: bias, bf16 store, per-channel sum/sumsq atomics.
__global__ __launch_bounds__(256) void conv_kernel(
    const float* __restrict__ x,
    const unsigned short* __restrict__ Whi, const unsigned short* __restrict__ Wlo,
    const float* __restrict__ Bv,
    unsigned short* __restrict__ Ybf,
    float* __restrict__ Sum, float* __restrict__ Sq)
{
    int lin = blockIdx.x;
    int vid = (lin & 7) * 160 + (lin >> 3);
    int o5  = vid % 5;
    int rem = vid / 5;            // 0..255
    int ob = o5 * 64;
    int n0 = (rem & 15) * 128;
    int b  = rem >> 4;

    int tid = threadIdx.x;
    int w = tid >> 6, lane = tid & 63;
    int quad = lane >> 4, l16 = lane & 15;
    int wo = w >> 1, wn = w & 1;

    __shared__ unsigned short Xh[128][40];   // [n_local][c_local], stride 80B
    __shared__ unsigned short Xl[128][40];

    int nl = tid & 127;       // n_local 0..127
    int ch = tid >> 7;        // c half
    const float* xb = x + (size_t)b * CH * NPT + n0 + nl;

    f32x4 acc[2][4];
#pragma unroll
    for (int ot = 0; ot < 2; ++ot)
#pragma unroll
        for (int nt = 0; nt < 4; ++nt)
            acc[ot][nt] = (f32x4){0.f, 0.f, 0.f, 0.f};

    float xv[16];
#pragma unroll
    for (int i = 0; i < 16; ++i)
        xv[i] = xb[(size_t)(ch * 16 + i) * NPT];

    for (int ks = 0; ks < 8; ++ks) {
        __syncthreads();
#pragma unroll
        for (int g = 0; g < 4; ++g) {
            ushort4 h4, l4;
            unsigned short* ph = (unsigned short*)&h4;
            unsigned short* pl = (unsigned short*)&l4;
#pragma unroll
            for (int j = 0; j < 4; ++j) {
                float f = xv[g * 4 + j];
                unsigned short h = f2bf(f);
                ph[j] = h;
                pl[j] = f2bf(f - bf2f(h));
            }
            *(ushort4*)&Xh[nl][ch * 16 + g * 4] = h4;
            *(ushort4*)&Xl[nl][ch * 16 + g * 4] = l4;
        }
        __syncthreads();

        if (ks < 7) {
#pragma unroll
            for (int i = 0; i < 16; ++i)
                xv[i] = xb[(size_t)((ks + 1) * 32 + ch * 16 + i) * NPT];
        }

        bf16x8 ah[2], al[2];
#pragma unroll
        for (int ot = 0; ot < 2; ++ot) {
            size_t orow = (size_t)(ob + wo * 32 + ot * 16 + l16) * 256 + ks * 32 + quad * 8;
            ah[ot] = *(const bf16x8*)(Whi + orow);
            al[ot] = *(const bf16x8*)(Wlo + orow);
        }
#pragma unroll
        for (int nt = 0; nt < 4; ++nt) {
            int nr = wn * 64 + nt * 16 + l16;
            bf16x8 bh = *(const bf16x8*)&Xh[nr][quad * 8];
            bf16x8 bl = *(const bf16x8*)&Xl[nr][quad * 8];
#pragma unroll
            for (int ot = 0; ot < 2; ++ot) {
                acc[ot][nt] = __builtin_amdgcn_mfma_f32_16x16x32_bf16(ah[ot], bh, acc[ot][nt], 0, 0, 0);
                acc[ot][nt] = __builtin_amdgcn_mfma_f32_16x16x32_bf16(ah[ot], bl, acc[ot][nt], 0, 0, 0);
                acc[ot][nt] = __builtin_amdgcn_mfma_f32_16x16x32_bf16(al[ot], bh, acc[ot][nt], 0, 0, 0);
            }
        }
    }

#pragma unroll
    for (int ot = 0; ot < 2; ++ot) {
        int obase = ob + wo * 32 + ot * 16 + quad * 4;
        float bias[4], sv[4], sq[4];
#pragma unroll
        for (int r = 0; r < 4; ++r) {
            bias[r] = Bv[obase + r];
            sv[r] = 0.f; sq[r] = 0.f;
        }
#pragma unroll
        for (int nt = 0; nt < 4; ++nt) {
            int n = n0 + wn * 64 + nt * 16 + l16;
#pragma unroll
            for (int r = 0; r < 4; ++r) {
                float v = acc[ot][nt][r] + bias[r];
                Ybf[((size_t)b * OTOT + obase + r) * NPT + n] = f2bf(v);
                sv[r] += v; sq[r] += v * v;
            }
        }
#pragma unroll
        for (int r = 0; r < 4; ++r) {
            float a = sv[r], q = sq[r];
            a += __shfl_xor(a, 1); q += __shfl_xor(q, 1);
            a += __shfl_xor(a, 2); q += __shfl_xor(q, 2);
            a += __shfl_xor(a, 4); q += __shfl_xor(q, 4);
            a += __shfl_xor(a, 8); q += __shfl_xor(q, 8);
            if (l16 == 0) {
                atomicAdd(&Sum[obase + r], a);
                atomicAdd(&Sq[obase + r], q);
            }
        }
    }
}

// ---------------------------------------------------------------------------
// Kernel 3: pack pass — v: affine+LeakyReLU -> Vbf [b][c][n];
//                       q/k: affine + transpose -> QKt [b][n][64].
// BN-finalize inlined per block (finalize_kernel removed). grid (32,16).
__global__ __launch_bounds__(256) void pack_kernel(
    const unsigned short* __restrict__ Ybf,
    const float* __restrict__ Sum, const float* __restrict__ Sq,
    const float* __restrict__ qg, const float* __restrict__ qbe,
    const float* __restrict__ kg, const float* __restrict__ kbe,
    const float* __restrict__ vg, const float* __restrict__ vbe,
    unsigned short* __restrict__ QKt, unsigned short* __restrict__ Vbf)
{
    int b = blockIdx.y, n0 = blockIdx.x * 64;
    int tid = threadIdx.x;

    __shared__ float sA[OTOT], sC[OTOT];
    for (int o = tid; o < OTOT; o += 256) {
        const float inv = 1.0f / (BATCH * NPT);
        float mean = Sum[o] * inv;
        float var  = Sq[o] * inv - mean * mean;
        float g, be;
        if (o < 32)      { g = qg[o];      be = qbe[o];      }
        else if (o < 64) { g = kg[o - 32]; be = kbe[o - 32]; }
        else             { g = vg[o - 64]; be = vbe[o - 64]; }
        float a = g * rsqrtf(var + EPSB);
        sA[o] = a;
        sC[o] = be - mean * a;
    }
    __syncthreads();

    for (int e = tid; e < 4096; e += 256) {
        int c = e >> 4, n4 = (e & 15) * 4;
        ushort4 v4 = *(const ushort4*)(Ybf + ((size_t)b * OTOT + 64 + c) * NPT + n0 + n4);
        float a = sA[64 + c], cc = sC[64 + c];
        ushort4 w4;
        unsigned short* pi = (unsigned short*)&v4;
        unsigned short* po = (unsigned short*)&w4;
#pragma unroll
        for (int i = 0; i < 4; ++i) {
            float y = bf2f(pi[i]) * a + cc;
            y = (y > 0.f) ? y : SLOPE * y;
            po[i] = f2bf(y);
        }
        *(ushort4*)(Vbf + ((size_t)b * CH + c) * NPT + n0 + n4) = w4;
    }

    __shared__ unsigned short T[64][72];
    for (int e = tid; e < 1024; e += 256) {
        int o = e >> 4, n4 = (e & 15) * 4;
        ushort4 v4 = *(const ushort4*)(Ybf + ((size_t)b * OTOT + o) * NPT + n0 + n4);
        float a = sA[o], cc = sC[o];
        unsigned short* pi = (unsigned short*)&v4;
#pragma unroll
        for (int i = 0; i < 4; ++i)
            T[n4 + i][o] = f2bf(bf2f(pi[i]) * a + cc);
    }
    __syncthreads();
    for (int e = tid; e < 1024; e += 256) {
        int nn = e >> 4, o4 = (e & 15) * 4;
        ushort4 v4 = *(const ushort4*)&T[nn][o4];
        *(ushort4*)(QKt + ((size_t)b * NPT + n0 + nn) * 64 + o4) = v4;
    }
}

// ---------------------------------------------------------------------------
// Kernel 4: MFMA flash attention, max-free softmax, + residual.
// v12 = v9 bit-exact (best passing: attn 86us, total 261.6us) + s_setprio(1/0)
//     around the PV MFMA cluster (T5; runtime arbitration hint, cannot alter
//     results). v11's 2-tile pairing failed correctness (absmax 17662) with
//     no mechanism identifiable by audit — third unexplained failure in the
//     multi-buffer restructure class (v4, v11) -> that direction is closed.
//     v9 structure: z-merged (one block covers all 256 c; wave w owns
//     c = w*64..+63), 2-buffer P with one __syncthreads per m-tile, hoisted
//     same-iteration V loads, rolling kb prefetch.
// grid 512 (XCD decode: 2 b per XCD -> K/V 2.5MB L2-resident), block 256,
// exactly 2 blocks/CU.
__global__ __launch_bounds__(256, 2) void attn_kernel(
    const unsigned short* __restrict__ QKt,
    const unsigned short* __restrict__ Vbf,
    const float* __restrict__ x,
    float* __restrict__ out)
{
    int L = blockIdx.x;
    int xcd = L & 7, k = L >> 3;      // k in [0,64)
    int gi = k >> 5, n0i = k & 31;    // gi in [0,2)
    int b = xcd * 2 + gi;             // [0,16)
    int n0 = n0i * 64;

    int tid = threadIdx.x;
    int w = tid >> 6, lane = tid & 63;
    int quad = lane >> 4, l16 = lane & 15;

    const unsigned short* QK = QKt + (size_t)b * NPT * 64;
    const unsigned short* V  = Vbf + (size_t)b * CH * NPT;

    __shared__ unsigned short Pbf[2][64][72];   // [buf][n][m], stride 144B
    __shared__ float rsw[4][64];
    __shared__ float rtot[64];

    // Q fragments: rows n = n0+nt*16+l16, k-slice quad*8
    bf16x8 qa[4];
#pragma unroll
    for (int nt = 0; nt < 4; ++nt)
        qa[nt] = *(const bf16x8*)(QK + ((size_t)(n0 + nt * 16 + l16)) * 64 + quad * 8);

    f32x4 acc[4][4];   // [nt][ct]: n = n0+nt*16+quad*4.., c = w*64+ct*16+l16
#pragma unroll
    for (int nt = 0; nt < 4; ++nt)
#pragma unroll
        for (int ct = 0; ct < 4; ++ct)
            acc[nt][ct] = (f32x4){0.f, 0.f, 0.f, 0.f};

    // per-lane softmax partials: n = nt*16+l16, m in {w*16+quad*4 ..+3} per tile
    float rsum[4];
#pragma unroll
    for (int nt = 0; nt < 4; ++nt) rsum[nt] = 0.f;

    const f32x4 zero4 = (f32x4){0.f, 0.f, 0.f, 0.f};

    // K fragment for m-tile 0: rows m = w*16+l16, k-slice quad*8 (K half: +32)
    bf16x8 kb = *(const bf16x8*)(QK + ((size_t)(w * 16 + l16)) * 64 + 32 + quad * 8);

    for (int mt = 0; mt < NPT / 64; ++mt) {
        unsigned short (*Pb)[72] = Pbf[mt & 1];

        // QK^T swapped: S[m = w*16+quad*4+r][n = nt*16+l16]
        f32x4 s[4];
#pragma unroll
        for (int nt = 0; nt < 4; ++nt)
            s[nt] = __builtin_amdgcn_mfma_f32_16x16x32_bf16(kb, qa[nt], zero4, 0, 0, 0);

        // prefetch next K tile; completes under exp/pack + barrier drain
        if (mt < NPT / 64 - 1)
            kb = *(const bf16x8*)(QK + ((size_t)((mt + 1) * 64 + w * 16 + l16)) * 64 + 32 + quad * 8);

        // V fragments for THIS tile (8 = ks2 x ct4), issued before exp/pack so
        // L2 latency hides under exp + barrier arrival (barrier drains vmcnt).
        bf16x8 vb[8];
#pragma unroll
        for (int u = 0; u < 8; ++u)
            vb[u] = *(const bf16x8*)(V + ((size_t)(w * 64 + (u & 3) * 16 + l16)) * NPT
                                     + mt * 64 + (u >> 2) * 32 + quad * 8);

#pragma unroll
        for (int nt = 0; nt < 4; ++nt) {
            float p0 = __expf(s[nt][0]);        // max-free: |s| << 88
            float p1 = __expf(s[nt][1]);
            float p2 = __expf(s[nt][2]);
            float p3 = __expf(s[nt][3]);
            rsum[nt] += (p0 + p1) + (p2 + p3);
            uint2 dd;
            dd.x = cvt_pk_bf16(p0, p1);
            dd.y = cvt_pk_bf16(p2, p3);
            // 4 m-consecutive bf16 at P[n][w*16+quad*4]; bank-floor pattern
            *(uint2*)&Pb[nt * 16 + l16][w * 16 + quad * 4] = dd;
        }

        __syncthreads();   // P[buf] visible; buffer alternation covers WAR

        __builtin_amdgcn_s_setprio(1);   // T5: favor PV MFMA waves vs the
                                         // other resident block's QK/exp phase
#pragma unroll
        for (int ks = 0; ks < 2; ++ks) {
            bf16x8 pa[4];
#pragma unroll
            for (int nt = 0; nt < 4; ++nt)
                pa[nt] = *(const bf16x8*)&Pbf[mt & 1][nt * 16 + l16][ks * 32 + quad * 8];
#pragma unroll
            for (int ct = 0; ct < 4; ++ct) {
                bf16x8 vv = vb[ks * 4 + ct];
#pragma unroll
                for (int nt = 0; nt < 4; ++nt)
                    acc[nt][ct] = __builtin_amdgcn_mfma_f32_16x16x32_bf16(pa[nt], vv, acc[nt][ct], 0, 0, 0);
            }
        }
        __builtin_amdgcn_s_setprio(0);
    }

    // reduce rsum over quads (m-subchunks), then over waves via LDS
#pragma unroll
    for (int nt = 0; nt < 4; ++nt) {
        float v = rsum[nt];
        v += __shfl_xor(v, 16);
        v += __shfl_xor(v, 32);
        if (lane < 16) rsw[w][nt * 16 + lane] = v;
    }
    __syncthreads();
    if (tid < 64)
        rtot[tid] = 1.0f / (rsw[0][tid] + rsw[1][tid] + rsw[2][tid] + rsw[3][tid]);
    __syncthreads();

    float rin[4][4];
#pragma unroll
    for (int nt = 0; nt < 4; ++nt)
#pragma unroll
        for (int r = 0; r < 4; ++r) rin[nt][r] = rtot[nt * 16 + quad * 4 + r];

#pragma unroll
    for (int nt = 0; nt < 4; ++nt)
#pragma unroll
        for (int ct = 0; ct < 4; ++ct) {
            int c = w * 64 + ct * 16 + l16;
            int n = n0 + nt * 16 + quad * 4;
            size_t gi4 = ((size_t)b * CH + c) * NPT + n;
            float4 xv = *(const float4*)(x + gi4);
            float4 o;
            o.x = acc[nt][ct][0] * rin[nt][0] + xv.x;
            o.y = acc[nt][ct][1] * rin[nt][1] + xv.y;
            o.z = acc[nt][ct][2] * rin[nt][2] + xv.z;
            o.w = acc[nt][ct][3] * rin[nt][3] + xv.w;
            *(float4*)(out + gi4) = o;
        }
}

// ---------------------------------------------------------------------------
extern "C" void kernel_launch(void* const* d_in, const int* in_sizes, int n_in,
                              void* d_out, int out_size, void* d_ws, size_t ws_size,
                              hipStream_t stream)
{
    const float* x   = (const float*)d_in[0];
    const float* qw  = (const float*)d_in[1];
    const float* qb  = (const float*)d_in[2];
    const float* qg  = (const float*)d_in[3];
    const float* qbe = (const float*)d_in[4];
    const float* kw  = (const float*)d_in[5];
    const float* kb  = (const float*)d_in[6];
    const float* kg  = (const float*)d_in[7];
    const float* kbe = (const float*)d_in[8];
    const float* vw  = (const float*)d_in[9];
    const float* vb  = (const float*)d_in[10];
    const float* vg  = (const float*)d_in[11];
    const float* vbe = (const float*)d_in[12];
    float* out = (float*)d_out;

    // ws: Ybf (21MB) | QKt (4.2MB; head reused as Whi/Wlo/Bv before pack) | Vbf (16.8MB)
    //     | Sum,Sq (2.5KB)
    unsigned short* Ybf = (unsigned short*)d_ws;
    unsigned short* QKt = Ybf + (size_t)BATCH * OTOT * NPT;          // 10,485,760 elems
    unsigned short* Vbf = QKt + (size_t)BATCH * NPT * 64;            // +2,097,152
    float* tail = (float*)(Vbf + (size_t)BATCH * CH * NPT);          // +8,388,608
    float* Sum = tail;
    float* Sq  = tail + OTOT;
    // overlay: Whi/Wlo/Bv live in QKt region, consumed (conv) before pack writes QKt
    unsigned short* Whi = QKt;                         // 81,920 ushorts
    unsigned short* Wlo = Whi + (size_t)CH * OTOT;     // 81,920 ushorts
    float* Bv = (float*)(Wlo + (size_t)CH * OTOT);     // 320 floats

    hipMemsetAsync(Sum, 0, 2 * OTOT * sizeof(float), stream);
    prep_kernel <<<320, 256, 0, stream>>>(qw, qb, kw, kb, vw, vb, Whi, Wlo, Bv);
    conv_kernel <<<1280, 256, 0, stream>>>(x, Whi, Wlo, Bv, Ybf, Sum, Sq);
    pack_kernel <<<dim3(NPT / 64, BATCH), 256, 0, stream>>>(
        Ybf, Sum, Sq, qg, qbe, kg, kbe, vg, vbe, QKt, Vbf);
    attn_kernel <<<512, 256, 0, stream>>>(QKt, Vbf, x, out);
}

// Round 14
// 256.545 us; speedup vs baseline: 1.2514x; 1.0141x over previous
//
#include <hip/hip_runtime.h>

#define BATCH 16
#define CH    256
#define NPT   2048
#define DQK   32
#define OTOT  320   // 32 q + 32 k + 256 v
#define EPSB  1e-5f
#define SLOPE 0.2f

typedef __attribute__((ext_vector_type(8))) short bf16x8;
typedef __attribute__((ext_vector_type(4))) float f32x4;

__device__ __forceinline__ unsigned short f2bf(float f) {
    unsigned u = __float_as_uint(f);
    u = (u + 0x7FFFu + ((u >> 16) & 1u)) >> 16;
    return (unsigned short)u;
}
__device__ __forceinline__ float bf2f(unsigned short h) {
    return __uint_as_float(((unsigned)h) << 16);
}
// pack two f32 -> dword of 2 bf16 (lo = a, hi = b), RNE in HW
__device__ __forceinline__ unsigned cvt_pk_bf16(float a, float b) {
    unsigned r;
    asm("v_cvt_pk_bf16_f32 %0, %1, %2" : "=v"(r) : "v"(a), "v"(b));
    return r;
}

// ---------------------------------------------------------------------------
// Kernel 0: split weights to Whi/Wlo bf16 [o][c] (A-frag layout) + bias Bv[o].
// grid 320 x 256.
__global__ __launch_bounds__(256) void prep_kernel(
    const float* __restrict__ qw, const float* __restrict__ qb,
    const float* __restrict__ kw, const float* __restrict__ kb,
    const float* __restrict__ vw, const float* __restrict__ vb,
    unsigned short* __restrict__ Whi, unsigned short* __restrict__ Wlo,
    float* __restrict__ Bv)
{
    int idx = blockIdx.x * 256 + threadIdx.x;   // < 81920
    int o = idx >> 8, c = idx & 255;
    float w;
    if (o < 32)      w = qw[(size_t)o * CH + c];
    else if (o < 64) w = kw[(size_t)(o - 32) * CH + c];
    else             w = vw[(size_t)(o - 64) * CH + c];
    unsigned short wh = f2bf(w);
    float rem = w - bf2f(wh);
    Whi[idx] = wh;
    Wlo[idx] = f2bf(rem);
    if (idx < OTOT) {
        int oo = idx;
        float bb;
        if (oo < 32)      bb = qb[oo];
        else if (oo < 64) bb = kb[oo - 32];
        else              bb = vb[oo - 64];
        Bv[oo] = bb;
    }
}

// ---------------------------------------------------------------------------
// Kernel 1: conv1x1 as bf16x3 MFMA GEMM (fp32-grade precision).
// Block: 64o x 128n for one b. grid 1280 linear, block 256 (waves 2o x 2n).
// XCD-chunked swizzle (1280 = 8*160) so the 5 o-blocks sharing one 128KB
// x-tile land on the SAME XCD -> x L2-resident.
// v13: DOUBLE-BUFFERED X staging (Xh/Xl[2]) -> ONE __syncthreads per k-step
//     (8 barriers/block instead of 16). Same 2-buffer 1-barrier alternation
//     proven in attn's Pbf: write buf[ks&1]; barrier; read buf[ks&1] — the
//     WAR on buf[ks&1] (write at ks+2 vs reads at ks) is separated by the
//     barrier at ks+1. MFMA order bit-identical. conv was barrier-bound
//     (MfmaUtil 6.5, VALU 15.7, HBM 5.9 — all idle at 95us).
// Fused: bias, bf16 store, per-channel sum/sumsq atomics.
__global__ __launch_bounds__(256) void conv_kernel(
    const float* __restrict__ x,
    const unsigned short* __restrict__ Whi, const unsigned short* __restrict__ Wlo,
    const float* __restrict__ Bv,
    unsigned short* __restrict__ Ybf,
    float* __restrict__ Sum, float* __restrict__ Sq)
{
    int lin = blockIdx.x;
    int vid = (lin & 7) * 160 + (lin >> 3);
    int o5  = vid % 5;
    int rem = vid / 5;            // 0..255
    int ob = o5 * 64;
    int n0 = (rem & 15) * 128;
    int b  = rem >> 4;

    int tid = threadIdx.x;
    int w = tid >> 6, lane = tid & 63;
    int quad = lane >> 4, l16 = lane & 15;
    int wo = w >> 1, wn = w & 1;

    __shared__ unsigned short Xh[2][128][40];   // [buf][n_local][c_local], stride 80B
    __shared__ unsigned short Xl[2][128][40];

    int nl = tid & 127;       // n_local 0..127
    int ch = tid >> 7;        // c half
    const float* xb = x + (size_t)b * CH * NPT + n0 + nl;

    f32x4 acc[2][4];
#pragma unroll
    for (int ot = 0; ot < 2; ++ot)
#pragma unroll
        for (int nt = 0; nt < 4; ++nt)
            acc[ot][nt] = (f32x4){0.f, 0.f, 0.f, 0.f};

    float xv[16];
#pragma unroll
    for (int i = 0; i < 16; ++i)
        xv[i] = xb[(size_t)(ch * 16 + i) * NPT];

    for (int ks = 0; ks < 8; ++ks) {
        unsigned short (*XhB)[40] = Xh[ks & 1];
        unsigned short (*XlB)[40] = Xl[ks & 1];
        // split + stage (transposed [n][c]) into buf ks&1
#pragma unroll
        for (int g = 0; g < 4; ++g) {
            ushort4 h4, l4;
            unsigned short* ph = (unsigned short*)&h4;
            unsigned short* pl = (unsigned short*)&l4;
#pragma unroll
            for (int j = 0; j < 4; ++j) {
                float f = xv[g * 4 + j];
                unsigned short h = f2bf(f);
                ph[j] = h;
                pl[j] = f2bf(f - bf2f(h));
            }
            *(ushort4*)&XhB[nl][ch * 16 + g * 4] = h4;
            *(ushort4*)&XlB[nl][ch * 16 + g * 4] = l4;
        }
        __syncthreads();   // tile visible; 2-buffer alternation covers WAR

        // prefetch next k-step while MFMA runs
        if (ks < 7) {
#pragma unroll
            for (int i = 0; i < 16; ++i)
                xv[i] = xb[(size_t)((ks + 1) * 32 + ch * 16 + i) * NPT];
        }

        // A fragments from global (L2/L3-resident, frag-layout exact)
        bf16x8 ah[2], al[2];
#pragma unroll
        for (int ot = 0; ot < 2; ++ot) {
            size_t orow = (size_t)(ob + wo * 32 + ot * 16 + l16) * 256 + ks * 32 + quad * 8;
            ah[ot] = *(const bf16x8*)(Whi + orow);
            al[ot] = *(const bf16x8*)(Wlo + orow);
        }
#pragma unroll
        for (int nt = 0; nt < 4; ++nt) {
            int nr = wn * 64 + nt * 16 + l16;
            bf16x8 bh = *(const bf16x8*)&XhB[nr][quad * 8];
            bf16x8 bl = *(const bf16x8*)&XlB[nr][quad * 8];
#pragma unroll
            for (int ot = 0; ot < 2; ++ot) {
                acc[ot][nt] = __builtin_amdgcn_mfma_f32_16x16x32_bf16(ah[ot], bh, acc[ot][nt], 0, 0, 0);
                acc[ot][nt] = __builtin_amdgcn_mfma_f32_16x16x32_bf16(ah[ot], bl, acc[ot][nt], 0, 0, 0);
                acc[ot][nt] = __builtin_amdgcn_mfma_f32_16x16x32_bf16(al[ot], bh, acc[ot][nt], 0, 0, 0);
            }
        }
    }

#pragma unroll
    for (int ot = 0; ot < 2; ++ot) {
        int obase = ob + wo * 32 + ot * 16 + quad * 4;
        float bias[4], sv[4], sq[4];
#pragma unroll
        for (int r = 0; r < 4; ++r) {
            bias[r] = Bv[obase + r];
            sv[r] = 0.f; sq[r] = 0.f;
        }
#pragma unroll
        for (int nt = 0; nt < 4; ++nt) {
            int n = n0 + wn * 64 + nt * 16 + l16;
#pragma unroll
            for (int r = 0; r < 4; ++r) {
                float v = acc[ot][nt][r] + bias[r];
                Ybf[((size_t)b * OTOT + obase + r) * NPT + n] = f2bf(v);
                sv[r] += v; sq[r] += v * v;
            }
        }
#pragma unroll
        for (int r = 0; r < 4; ++r) {
            float a = sv[r], q = sq[r];
            a += __shfl_xor(a, 1); q += __shfl_xor(q, 1);
            a += __shfl_xor(a, 2); q += __shfl_xor(q, 2);
            a += __shfl_xor(a, 4); q += __shfl_xor(q, 4);
            a += __shfl_xor(a, 8); q += __shfl_xor(q, 8);
            if (l16 == 0) {
                atomicAdd(&Sum[obase + r], a);
                atomicAdd(&Sq[obase + r], q);
            }
        }
    }
}

// ---------------------------------------------------------------------------
// Kernel 3: pack pass — v: affine+LeakyReLU -> Vbf [b][c][n];
//                       q/k: affine + transpose -> QKt [b][n][64].
// BN-finalize inlined per block (finalize_kernel removed). grid (32,16).
__global__ __launch_bounds__(256) void pack_kernel(
    const unsigned short* __restrict__ Ybf,
    const float* __restrict__ Sum, const float* __restrict__ Sq,
    const float* __restrict__ qg, const float* __restrict__ qbe,
    const float* __restrict__ kg, const float* __restrict__ kbe,
    const float* __restrict__ vg, const float* __restrict__ vbe,
    unsigned short* __restrict__ QKt, unsigned short* __restrict__ Vbf)
{
    int b = blockIdx.y, n0 = blockIdx.x * 64;
    int tid = threadIdx.x;

    __shared__ float sA[OTOT], sC[OTOT];
    for (int o = tid; o < OTOT; o += 256) {
        const float inv = 1.0f / (BATCH * NPT);
        float mean = Sum[o] * inv;
        float var  = Sq[o] * inv - mean * mean;
        float g, be;
        if (o < 32)      { g = qg[o];      be = qbe[o];      }
        else if (o < 64) { g = kg[o - 32]; be = kbe[o - 32]; }
        else             { g = vg[o - 64]; be = vbe[o - 64]; }
        float a = g * rsqrtf(var + EPSB);
        sA[o] = a;
        sC[o] = be - mean * a;
    }
    __syncthreads();

    for (int e = tid; e < 4096; e += 256) {
        int c = e >> 4, n4 = (e & 15) * 4;
        ushort4 v4 = *(const ushort4*)(Ybf + ((size_t)b * OTOT + 64 + c) * NPT + n0 + n4);
        float a = sA[64 + c], cc = sC[64 + c];
        ushort4 w4;
        unsigned short* pi = (unsigned short*)&v4;
        unsigned short* po = (unsigned short*)&w4;
#pragma unroll
        for (int i = 0; i < 4; ++i) {
            float y = bf2f(pi[i]) * a + cc;
            y = (y > 0.f) ? y : SLOPE * y;
            po[i] = f2bf(y);
        }
        *(ushort4*)(Vbf + ((size_t)b * CH + c) * NPT + n0 + n4) = w4;
    }

    __shared__ unsigned short T[64][72];
    for (int e = tid; e < 1024; e += 256) {
        int o = e >> 4, n4 = (e & 15) * 4;
        ushort4 v4 = *(const ushort4*)(Ybf + ((size_t)b * OTOT + o) * NPT + n0 + n4);
        float a = sA[o], cc = sC[o];
        unsigned short* pi = (unsigned short*)&v4;
#pragma unroll
        for (int i = 0; i < 4; ++i)
            T[n4 + i][o] = f2bf(bf2f(pi[i]) * a + cc);
    }
    __syncthreads();
    for (int e = tid; e < 1024; e += 256) {
        int nn = e >> 4, o4 = (e & 15) * 4;
        ushort4 v4 = *(const ushort4*)&T[nn][o4];
        *(ushort4*)(QKt + ((size_t)b * NPT + n0 + nn) * 64 + o4) = v4;
    }
}

// ---------------------------------------------------------------------------
// Kernel 4: MFMA flash attention, max-free softmax, + residual.
// v12 (passed, kept bit-exact): v9 z-merged structure + s_setprio(1/0) around
//     the PV MFMA cluster. One block covers all 256 c (wave w owns
//     c = w*64..+63), 2-buffer P with one __syncthreads per m-tile, hoisted
//     same-iteration V loads, rolling kb prefetch.
// grid 512 (XCD decode: 2 b per XCD -> K/V 2.5MB L2-resident), block 256,
// exactly 2 blocks/CU.
__global__ __launch_bounds__(256, 2) void attn_kernel(
    const unsigned short* __restrict__ QKt,
    const unsigned short* __restrict__ Vbf,
    const float* __restrict__ x,
    float* __restrict__ out)
{
    int L = blockIdx.x;
    int xcd = L & 7, k = L >> 3;      // k in [0,64)
    int gi = k >> 5, n0i = k & 31;    // gi in [0,2)
    int b = xcd * 2 + gi;             // [0,16)
    int n0 = n0i * 64;

    int tid = threadIdx.x;
    int w = tid >> 6, lane = tid & 63;
    int quad = lane >> 4, l16 = lane & 15;

    const unsigned short* QK = QKt + (size_t)b * NPT * 64;
    const unsigned short* V  = Vbf + (size_t)b * CH * NPT;

    __shared__ unsigned short Pbf[2][64][72];   // [buf][n][m], stride 144B
    __shared__ float rsw[4][64];
    __shared__ float rtot[64];

    // Q fragments: rows n = n0+nt*16+l16, k-slice quad*8
    bf16x8 qa[4];
#pragma unroll
    for (int nt = 0; nt < 4; ++nt)
        qa[nt] = *(const bf16x8*)(QK + ((size_t)(n0 + nt * 16 + l16)) * 64 + quad * 8);

    f32x4 acc[4][4];   // [nt][ct]: n = n0+nt*16+quad*4.., c = w*64+ct*16+l16
#pragma unroll
    for (int nt = 0; nt < 4; ++nt)
#pragma unroll
        for (int ct = 0; ct < 4; ++ct)
            acc[nt][ct] = (f32x4){0.f, 0.f, 0.f, 0.f};

    // per-lane softmax partials: n = nt*16+l16, m in {w*16+quad*4 ..+3} per tile
    float rsum[4];
#pragma unroll
    for (int nt = 0; nt < 4; ++nt) rsum[nt] = 0.f;

    const f32x4 zero4 = (f32x4){0.f, 0.f, 0.f, 0.f};

    // K fragment for m-tile 0: rows m = w*16+l16, k-slice quad*8 (K half: +32)
    bf16x8 kb = *(const bf16x8*)(QK + ((size_t)(w * 16 + l16)) * 64 + 32 + quad * 8);

    for (int mt = 0; mt < NPT / 64; ++mt) {
        unsigned short (*Pb)[72] = Pbf[mt & 1];

        // QK^T swapped: S[m = w*16+quad*4+r][n = nt*16+l16]
        f32x4 s[4];
#pragma unroll
        for (int nt = 0; nt < 4; ++nt)
            s[nt] = __builtin_amdgcn_mfma_f32_16x16x32_bf16(kb, qa[nt], zero4, 0, 0, 0);

        // prefetch next K tile; completes under exp/pack + barrier drain
        if (mt < NPT / 64 - 1)
            kb = *(const bf16x8*)(QK + ((size_t)((mt + 1) * 64 + w * 16 + l16)) * 64 + 32 + quad * 8);

        // V fragments for THIS tile (8 = ks2 x ct4), issued before exp/pack so
        // L2 latency hides under exp + barrier arrival (barrier drains vmcnt).
        bf16x8 vb[8];
#pragma unroll
        for (int u = 0; u < 8; ++u)
            vb[u] = *(const bf16x8*)(V + ((size_t)(w * 64 + (u & 3) * 16 + l16)) * NPT
                                     + mt * 64 + (u >> 2) * 32 + quad * 8);

#pragma unroll
        for (int nt = 0; nt < 4; ++nt) {
            float p0 = __expf(s[nt][0]);        // max-free: |s| << 88
            float p1 = __expf(s[nt][1]);
            float p2 = __expf(s[nt][2]);
            float p3 = __expf(s[nt][3]);
            rsum[nt] += (p0 + p1) + (p2 + p3);
            uint2 dd;
            dd.x = cvt_pk_bf16(p0, p1);
            dd.y = cvt_pk_bf16(p2, p3);
            // 4 m-consecutive bf16 at P[n][w*16+quad*4]; bank-floor pattern
            *(uint2*)&Pb[nt * 16 + l16][w * 16 + quad * 4] = dd;
        }

        __syncthreads();   // P[buf] visible; buffer alternation covers WAR

        __builtin_amdgcn_s_setprio(1);   // T5: favor PV MFMA waves vs the
                                         // other resident block's QK/exp phase
#pragma unroll
        for (int ks = 0; ks < 2; ++ks) {
            bf16x8 pa[4];
#pragma unroll
            for (int nt = 0; nt < 4; ++nt)
                pa[nt] = *(const bf16x8*)&Pbf[mt & 1][nt * 16 + l16][ks * 32 + quad * 8];
#pragma unroll
            for (int ct = 0; ct < 4; ++ct) {
                bf16x8 vv = vb[ks * 4 + ct];
#pragma unroll
                for (int nt = 0; nt < 4; ++nt)
                    acc[nt][ct] = __builtin_amdgcn_mfma_f32_16x16x32_bf16(pa[nt], vv, acc[nt][ct], 0, 0, 0);
            }
        }
        __builtin_amdgcn_s_setprio(0);
    }

    // reduce rsum over quads (m-subchunks), then over waves via LDS
#pragma unroll
    for (int nt = 0; nt < 4; ++nt) {
        float v = rsum[nt];
        v += __shfl_xor(v, 16);
        v += __shfl_xor(v, 32);
        if (lane < 16) rsw[w][nt * 16 + lane] = v;
    }
    __syncthreads();
    if (tid < 64)
        rtot[tid] = 1.0f / (rsw[0][tid] + rsw[1][tid] + rsw[2][tid] + rsw[3][tid]);
    __syncthreads();

    float rin[4][4];
#pragma unroll
    for (int nt = 0; nt < 4; ++nt)
#pragma unroll
        for (int r = 0; r < 4; ++r) rin[nt][r] = rtot[nt * 16 + quad * 4 + r];

#pragma unroll
    for (int nt = 0; nt < 4; ++nt)
#pragma unroll
        for (int ct = 0; ct < 4; ++ct) {
            int c = w * 64 + ct * 16 + l16;
            int n = n0 + nt * 16 + quad * 4;
            size_t gi4 = ((size_t)b * CH + c) * NPT + n;
            float4 xv = *(const float4*)(x + gi4);
            float4 o;
            o.x = acc[nt][ct][0] * rin[nt][0] + xv.x;
            o.y = acc[nt][ct][1] * rin[nt][1] + xv.y;
            o.z = acc[nt][ct][2] * rin[nt][2] + xv.z;
            o.w = acc[nt][ct][3] * rin[nt][3] + xv.w;
            *(float4*)(out + gi4) = o;
        }
}

// ---------------------------------------------------------------------------
extern "C" void kernel_launch(void* const* d_in, const int* in_sizes, int n_in,
                              void* d_out, int out_size, void* d_ws, size_t ws_size,
                              hipStream_t stream)
{
    const float* x   = (const float*)d_in[0];
    const float* qw  = (const float*)d_in[1];
    const float* qb  = (const float*)d_in[2];
    const float* qg  = (const float*)d_in[3];
    const float* qbe = (const float*)d_in[4];
    const float* kw  = (const float*)d_in[5];
    const float* kb  = (const float*)d_in[6];
    const float* kg  = (const float*)d_in[7];
    const float* kbe = (const float*)d_in[8];
    const float* vw  = (const float*)d_in[9];
    const float* vb  = (const float*)d_in[10];
    const float* vg  = (const float*)d_in[11];
    const float* vbe = (const float*)d_in[12];
    float* out = (float*)d_out;

    // ws: Ybf (21MB) | QKt (4.2MB; head reused as Whi/Wlo/Bv before pack) | Vbf (16.8MB)
    //     | Sum,Sq (2.5KB)
    unsigned short* Ybf = (unsigned short*)d_ws;
    unsigned short* QKt = Ybf + (size_t)BATCH * OTOT * NPT;          // 10,485,760 elems
    unsigned short* Vbf = QKt + (size_t)BATCH * NPT * 64;            // +2,097,152
    float* tail = (float*)(Vbf + (size_t)BATCH * CH * NPT);          // +8,388,608
    float* Sum = tail;
    float* Sq  = tail + OTOT;
    // overlay: Whi/Wlo/Bv live in QKt region, consumed (conv) before pack writes QKt
    unsigned short* Whi = QKt;                         // 81,920 ushorts
    unsigned short* Wlo = Whi + (size_t)CH * OTOT;     // 81,920 ushorts
    float* Bv = (float*)(Wlo + (size_t)CH * OTOT);     // 320 floats

    hipMemsetAsync(Sum, 0, 2 * OTOT * sizeof(float), stream);
    prep_kernel <<<320, 256, 0, stream>>>(qw, qb, kw, kb, vw, vb, Whi, Wlo, Bv);
    conv_kernel <<<1280, 256, 0, stream>>>(x, Whi, Wlo, Bv, Ybf, Sum, Sq);
    pack_kernel <<<dim3(NPT / 64, BATCH), 256, 0, stream>>>(
        Ybf, Sum, Sq, qg, qbe, kg, kbe, vg, vbe, QKt, Vbf);
    attn_kernel <<<512, 256, 0, stream>>>(QKt, Vbf, x, out);
}